// Round 1
// baseline (817.194 us; speedup 1.0000x reference)
//
#include <hip/hip_runtime.h>
#include <cstdint>
#include <cstddef>

// Problem constants: B=8, C=128, N=512, T=64, k_sel = int(0.8*512) = 409
#define KSEL 409u

// Workspace layout (float offsets)
#define OFF_YW   0u          // 33554432  yw[b,d,n,t] = P@x + pb
#define OFF_XS   33554432u   // 524288    Xs[b,n,c'] = sum_t x
#define OFF_H    34078720u   // 524288    h[b,n,c]
#define OFF_HT   34603008u   // 524288    hT[b,c,n]
#define OFF_WH1  35127296u   // 4096
#define OFF_WH2  35131392u   // 4096
#define OFF_ADJ  35135488u   // 2097152   adj[b,n,m] (post-topk)
#define OFF_MEMT 37232640u   // 65536     memT[c,m]
#define OFF_WWT  37298176u   // 16384     WwT[c',c] = W_w[c,c']
#define OFF_M    37314560u   // 16384     M = conv_w @ theta^T
#define OFF_PT   37330944u   // 16384     PT[c,d] = (M@W_w)[d,c]
#define OFF_PB   37347328u   // 128       pb = M @ W_b
// total 37347456 floats = 149.4 MB

// ---------------- pre-kernels (tiny) ----------------
__global__ __launch_bounds__(256) void k_pre1(
    const float* __restrict__ memory, const float* __restrict__ W_w,
    const float* __restrict__ conv_w, const float* __restrict__ theta,
    float* __restrict__ memT, float* __restrict__ WwT, float* __restrict__ Mm) {
  int idx = blockIdx.x * 256 + threadIdx.x;
  if (idx < 65536) {                       // memT[c*512+m] = memory[m,c]
    int c = idx >> 9, m = idx & 511;
    memT[idx] = memory[m * 128 + c];
  } else if (idx < 81920) {                // WwT[c'*128+c] = W_w[c,c']
    int i2 = idx - 65536;
    int cp = i2 >> 7, c = i2 & 127;
    WwT[i2] = W_w[c * 128 + cp];
  } else if (idx < 98304) {                // M[d,e] = sum_c conv_w[d,c]*theta[e,c]
    int i3 = idx - 81920;
    int d = i3 >> 7, e = i3 & 127;
    float s = 0.f;
    for (int c = 0; c < 128; ++c) s += conv_w[d * 128 + c] * theta[e * 128 + c];
    Mm[i3] = s;
  }
}

__global__ __launch_bounds__(256) void k_pre2(
    const float* __restrict__ Mm, const float* __restrict__ W_w,
    const float* __restrict__ W_b, float* __restrict__ PT, float* __restrict__ pb) {
  int idx = blockIdx.x * 256 + threadIdx.x;
  if (idx < 16384) {                       // PT[c*128+d] = sum_e M[d,e]*W_w[e,c]
    int c = idx >> 7, d = idx & 127;
    float s = 0.f;
    for (int e = 0; e < 128; ++e) s += Mm[d * 128 + e] * W_w[e * 128 + c];
    PT[idx] = s;
    if (idx < 128) {
      float s2 = 0.f;
      for (int e = 0; e < 128; ++e) s2 += Mm[idx * 128 + e] * W_b[e];
      pb[idx] = s2;
    }
  }
}

// ---------------- k_yw: yw[b,d,n,t] = sum_c PT[c,d]*x[b,c,n,t] + pb[d]; Xs[b,n,c]=sum_t x ----
// one block per (b,n); 128 threads, 8x8 micro-tile over (d,t)
__global__ __launch_bounds__(128) void k_yw(
    const float* __restrict__ x, const float* __restrict__ PT,
    const float* __restrict__ pb, float* __restrict__ yw, float* __restrict__ Xs) {
  __shared__ float xt[128 * 68];   // x tile [c][t], stride 68 (16B aligned, low-conflict)
  __shared__ float pt[32 * 128];   // PT chunk [c_local][d]
  int bid = blockIdx.x;
  int b = bid >> 9, n = bid & 511;
  int tid = threadIdx.x;
  const float* xbase = x + (size_t)b * (128 * 512 * 64) + (size_t)n * 64;
  for (int k = 0; k < 64; ++k) {
    int idx = tid + k * 128;
    int c = idx >> 6, t = idx & 63;
    xt[c * 68 + t] = xbase[(size_t)c * 32768 + t];
  }
  __syncthreads();
  {
    float s = 0.f;
    #pragma unroll
    for (int t = 0; t < 64; ++t) s += xt[tid * 68 + t];
    Xs[(size_t)(b * 512 + n) * 128 + tid] = s;
  }
  int dt = tid & 7, dy = tid >> 3;
  int t0 = dt * 8, d0 = dy * 8;
  float acc[8][8];
  #pragma unroll
  for (int i = 0; i < 8; ++i)
    #pragma unroll
    for (int j = 0; j < 8; ++j) acc[i][j] = 0.f;
  for (int cc = 0; cc < 4; ++cc) {
    int c0 = cc * 32;
    for (int k = 0; k < 32; ++k) {
      int idx = tid + k * 128;
      pt[idx] = PT[(size_t)(c0 + (idx >> 7)) * 128 + (idx & 127)];
    }
    __syncthreads();
    #pragma unroll 4
    for (int i = 0; i < 32; ++i) {
      int c = c0 + i;
      float4 a0 = *(const float4*)&pt[i * 128 + d0];
      float4 a1 = *(const float4*)&pt[i * 128 + d0 + 4];
      float4 b0 = *(const float4*)&xt[c * 68 + t0];
      float4 b1 = *(const float4*)&xt[c * 68 + t0 + 4];
      float av[8] = {a0.x, a0.y, a0.z, a0.w, a1.x, a1.y, a1.z, a1.w};
      float bv[8] = {b0.x, b0.y, b0.z, b0.w, b1.x, b1.y, b1.z, b1.w};
      #pragma unroll
      for (int jd = 0; jd < 8; ++jd)
        #pragma unroll
        for (int jt = 0; jt < 8; ++jt) acc[jd][jt] += av[jd] * bv[jt];
    }
    __syncthreads();
  }
  size_t outb = (size_t)b * (128 * 512 * 64) + (size_t)n * 64 + t0;
  #pragma unroll
  for (int jd = 0; jd < 8; ++jd) {
    int d = d0 + jd;
    float bias = pb[d];
    float4 o0, o1;
    o0.x = acc[jd][0] + bias; o0.y = acc[jd][1] + bias;
    o0.z = acc[jd][2] + bias; o0.w = acc[jd][3] + bias;
    o1.x = acc[jd][4] + bias; o1.y = acc[jd][5] + bias;
    o1.z = acc[jd][6] + bias; o1.w = acc[jd][7] + bias;
    *(float4*)&yw[outb + (size_t)d * 32768] = o0;
    *(float4*)&yw[outb + (size_t)d * 32768 + 4] = o1;
  }
}

// ---------------- k_h: h[b,n,c] = sum_c' W_w[c,c']*Xs[b,n,c'] + 64*W_b[c]; also hT, Wh1, Wh2 ----
__global__ __launch_bounds__(256) void k_h(
    const float* __restrict__ Xs, const float* __restrict__ WwT,
    const float* __restrict__ W_b, const float* __restrict__ a_vec,
    float* __restrict__ h, float* __restrict__ hT,
    float* __restrict__ Wh1, float* __restrict__ Wh2) {
  __shared__ float wt[64 * 128];
  __shared__ float xs[8 * 128];
  __shared__ float hr[8 * 128];
  __shared__ float av[256];
  int tid = threadIdx.x;
  int row0 = blockIdx.x * 8;   // global bn row
  for (int i = tid; i < 1024; i += 256) xs[i] = Xs[(size_t)row0 * 128 + i];
  av[tid] = a_vec[tid];
  int c = tid & 127;
  int r0 = tid >> 7;
  float wb = W_b[c] * 64.f;
  float acc[4];
  #pragma unroll
  for (int k = 0; k < 4; ++k) acc[k] = wb;
  for (int ch = 0; ch < 2; ++ch) {
    int cp0 = ch * 64;
    __syncthreads();
    for (int i = tid; i < 8192; i += 256) wt[i] = WwT[(size_t)cp0 * 128 + i];
    __syncthreads();
    for (int cpl = 0; cpl < 64; ++cpl) {
      float w = wt[cpl * 128 + c];
      #pragma unroll
      for (int k = 0; k < 4; ++k) acc[k] += xs[(r0 + 2 * k) * 128 + cp0 + cpl] * w;
    }
  }
  #pragma unroll
  for (int k = 0; k < 4; ++k) {
    int r = r0 + 2 * k;
    int rowg = row0 + r;
    int b = rowg >> 9, n = rowg & 511;
    h[(size_t)rowg * 128 + c] = acc[k];
    hT[((size_t)(b * 128 + c)) * 512 + n] = acc[k];
    hr[r * 128 + c] = acc[k];
  }
  __syncthreads();
  if (tid < 8) {
    float w1 = 0.f, w2 = 0.f;
    for (int cc = 0; cc < 128; ++cc) {
      float hv = hr[tid * 128 + cc];
      w1 += hv * av[cc];
      w2 += hv * av[128 + cc];
    }
    Wh1[row0 + tid] = w1;
    Wh2[row0 + tid] = w2;
  }
}

// ---------------- adjacency helpers ----------------
__device__ __forceinline__ void reduce_rows4(float v[4], float* sred, int tid, bool domax) {
  int lane = tid & 63, wid = tid >> 6;
  #pragma unroll
  for (int off = 32; off > 0; off >>= 1) {
    #pragma unroll
    for (int r = 0; r < 4; ++r) {
      float o = __shfl_down(v[r], off, 64);
      v[r] = domax ? fmaxf(v[r], o) : (v[r] + o);
    }
  }
  if (lane == 0) {
    #pragma unroll
    for (int r = 0; r < 4; ++r) sred[r * 4 + wid] = v[r];
  }
  __syncthreads();
  #pragma unroll
  for (int r = 0; r < 4; ++r) {
    float a0 = sred[r * 4 + 0], a1 = sred[r * 4 + 1];
    float a2 = sred[r * 4 + 2], a3 = sred[r * 4 + 3];
    v[r] = domax ? fmaxf(fmaxf(a0, a1), fmaxf(a2, a3)) : (a0 + a1 + a2 + a3);
  }
  __syncthreads();
}

__device__ __forceinline__ void softmax_rows4(float v[4][2], float* sred, int tid) {
  float mx[4];
  #pragma unroll
  for (int r = 0; r < 4; ++r) mx[r] = fmaxf(v[r][0], v[r][1]);
  reduce_rows4(mx, sred, tid, true);
  float sm[4];
  #pragma unroll
  for (int r = 0; r < 4; ++r) {
    v[r][0] = expf(v[r][0] - mx[r]);
    v[r][1] = expf(v[r][1] - mx[r]);
    sm[r] = v[r][0] + v[r][1];
  }
  reduce_rows4(sm, sred, tid, false);
  #pragma unroll
  for (int r = 0; r < 4; ++r) {
    float inv = 1.f / sm[r];
    v[r][0] *= inv;
    v[r][1] *= inv;
  }
}

// ---------------- k_adj: full adjacency + softmaxes + exact top-409 mask ----------------
// one block per (b, 4 rows of n); 256 threads, each handles m = tid and tid+256
__global__ __launch_bounds__(256) void k_adj(
    const float* __restrict__ h, const float* __restrict__ hT,
    const float* __restrict__ memT, const float* __restrict__ Wh1,
    const float* __restrict__ Wh2, const float* __restrict__ cw,
    const float* __restrict__ cwa, const float* __restrict__ fc_w,
    const float* __restrict__ fc_b, float* __restrict__ adj) {
  __shared__ float hn[4 * 128];
  __shared__ float sred[16];
  __shared__ unsigned scnt[124];
  int tid = threadIdx.x;
  int b = blockIdx.x >> 7;
  int n0 = (blockIdx.x & 127) * 4;
  for (int i = tid; i < 512; i += 256) hn[i] = h[((size_t)(b * 512 + n0)) * 128 + i];
  for (int i = tid; i < 124; i += 256) scnt[i] = 0u;
  __syncthreads();
  int m0 = tid, m1 = tid + 256;
  float d1[4][2] = {}, d2[4][2] = {};
  for (int c = 0; c < 128; ++c) {
    float mv0 = memT[c * 512 + m0];
    float mv1 = memT[c * 512 + m1];
    const float* hTr = hT + ((size_t)(b * 128 + c)) * 512;
    float hv0 = hTr[m0];
    float hv1 = hTr[m1];
    #pragma unroll
    for (int r = 0; r < 4; ++r) {
      float hc = hn[r * 128 + c];
      d1[r][0] += hc * mv0; d1[r][1] += hc * mv1;
      d2[r][0] += hc * hv0; d2[r][1] += hc * hv1;
    }
  }
  const float scale = 0.08838834764831845f;   // 1/sqrt(128)
  float l1[4][2], l2[4][2];
  #pragma unroll
  for (int r = 0; r < 4; ++r)
    #pragma unroll
    for (int s = 0; s < 2; ++s) {
      l1[r][s] = fmaxf(d1[r][s] * scale, 0.f);
      l2[r][s] = fmaxf(d2[r][s] * scale, 0.f);
    }
  softmax_rows4(l1, sred, tid);
  softmax_rows4(l2, sred, tid);
  float f0 = fc_w[0], f1 = fc_w[1], fb = fc_b[0];
  float wh2v[2] = {Wh2[b * 512 + m0], Wh2[b * 512 + m1]};
  float aw[4][2];
  #pragma unroll
  for (int r = 0; r < 4; ++r) {
    int n = n0 + r;
    float wh1v = Wh1[b * 512 + n];
    #pragma unroll
    for (int s = 0; s < 2; ++s) {
      int m = s ? m1 : m0;
      float e = wh1v + wh2v[s];
      float adjf = f0 * l1[r][s] + f1 * l2[r][s] + fb;
      aw[r][s] = e * cw[n * 512 + m] + adjf * cwa[n * 512 + m];
    }
  }
  softmax_rows4(aw, sred, tid);
  // exact top-k: kth-largest per row via bitwise binary search on positive-float bits
  unsigned ua[4][2];
  #pragma unroll
  for (int r = 0; r < 4; ++r) {
    ua[r][0] = __float_as_uint(aw[r][0]);
    ua[r][1] = __float_as_uint(aw[r][1]);
  }
  unsigned cand[4] = {0u, 0u, 0u, 0u};
  int lane = tid & 63;
  for (int bit = 30; bit >= 0; --bit) {
    unsigned msk = 1u << bit;
    #pragma unroll
    for (int r = 0; r < 4; ++r) {
      unsigned tst = cand[r] | msk;
      unsigned long long b0 = __ballot(ua[r][0] >= tst);
      unsigned long long b1 = __ballot(ua[r][1] >= tst);
      if (lane == 0)
        atomicAdd(&scnt[bit * 4 + r], (unsigned)(__popcll(b0) + __popcll(b1)));
    }
    __syncthreads();
    #pragma unroll
    for (int r = 0; r < 4; ++r)
      if (scnt[bit * 4 + r] >= KSEL) cand[r] |= msk;
  }
  #pragma unroll
  for (int r = 0; r < 4; ++r) {
    size_t base = ((size_t)(b * 512 + n0 + r)) * 512;
    adj[base + m0] = (ua[r][0] >= cand[r]) ? aw[r][0] : 0.f;
    adj[base + m1] = (ua[r][1] >= cand[r]) ? aw[r][1] : 0.f;
  }
}

// ---------------- k_out: out[b,d,m,t] = (conv_b[d] + sum_n adj[b,n,m]*yw[b,d,n,t])*emb[d,m] + x ----
// one block per (b, d, m-tile of 128); 128 threads, 8x8 micro-tile over (m,t)
__global__ __launch_bounds__(128) void k_out(
    const float* __restrict__ yw, const float* __restrict__ adj,
    const float* __restrict__ conv_b, const float* __restrict__ emb,
    const float* __restrict__ x, float* __restrict__ out) {
  __shared__ float ly[32 * 64];
  __shared__ float la[32 * 128];
  int tid = threadIdx.x;
  int gid = blockIdx.x;
  int b = gid >> 9;
  int rest = gid & 511;
  int d = rest >> 2;
  int mt = rest & 3;
  int ty = tid & 7, tx = tid >> 3;
  int t0 = ty * 8, ml0 = tx * 8;
  float acc[8][8];
  #pragma unroll
  for (int i = 0; i < 8; ++i)
    #pragma unroll
    for (int j = 0; j < 8; ++j) acc[i][j] = 0.f;
  const float* ywb = yw + ((size_t)(b * 128 + d)) * 32768;
  const float* adjb = adj + (size_t)b * (512 * 512) + mt * 128;
  for (int nc = 0; nc < 16; ++nc) {
    int nn0 = nc * 32;
    for (int k = 0; k < 16; ++k) {
      int idx = tid + k * 128;
      ly[idx] = ywb[(size_t)nn0 * 64 + idx];
    }
    for (int k = 0; k < 32; ++k) {
      int idx = tid + k * 128;
      int i = idx >> 7, m = idx & 127;
      la[idx] = adjb[((size_t)(nn0 + i)) * 512 + m];
    }
    __syncthreads();
    #pragma unroll 4
    for (int i = 0; i < 32; ++i) {
      float4 y0 = *(const float4*)&ly[i * 64 + t0];
      float4 y1 = *(const float4*)&ly[i * 64 + t0 + 4];
      float4 a0 = *(const float4*)&la[i * 128 + ml0];
      float4 a1 = *(const float4*)&la[i * 128 + ml0 + 4];
      float avv[8] = {a0.x, a0.y, a0.z, a0.w, a1.x, a1.y, a1.z, a1.w};
      float yv[8] = {y0.x, y0.y, y0.z, y0.w, y1.x, y1.y, y1.z, y1.w};
      #pragma unroll
      for (int jm = 0; jm < 8; ++jm)
        #pragma unroll
        for (int jt = 0; jt < 8; ++jt) acc[jm][jt] += avv[jm] * yv[jt];
    }
    __syncthreads();
  }
  float cb = conv_b[d];
  int mg = mt * 128 + ml0;
  #pragma unroll
  for (int jm = 0; jm < 8; ++jm) {
    int m = mg + jm;
    float em = emb[d * 512 + m];
    size_t base = (((size_t)(b * 128 + d)) * 512 + m) * 64 + t0;
    float4 xv0 = *(const float4*)&x[base];
    float4 xv1 = *(const float4*)&x[base + 4];
    float4 o0, o1;
    o0.x = (acc[jm][0] + cb) * em + xv0.x;
    o0.y = (acc[jm][1] + cb) * em + xv0.y;
    o0.z = (acc[jm][2] + cb) * em + xv0.z;
    o0.w = (acc[jm][3] + cb) * em + xv0.w;
    o1.x = (acc[jm][4] + cb) * em + xv1.x;
    o1.y = (acc[jm][5] + cb) * em + xv1.y;
    o1.z = (acc[jm][6] + cb) * em + xv1.z;
    o1.w = (acc[jm][7] + cb) * em + xv1.w;
    *(float4*)&out[base] = o0;
    *(float4*)&out[base + 4] = o1;
  }
}

extern "C" void kernel_launch(void* const* d_in, const int* in_sizes, int n_in,
                              void* d_out, int out_size, void* d_ws, size_t ws_size,
                              hipStream_t stream) {
  const float* x      = (const float*)d_in[0];
  const float* W_w    = (const float*)d_in[1];
  const float* W_b    = (const float*)d_in[2];
  const float* conv_w = (const float*)d_in[3];
  const float* conv_b = (const float*)d_in[4];
  const float* theta  = (const float*)d_in[5];
  const float* memory = (const float*)d_in[6];
  const float* a_vec  = (const float*)d_in[7];
  const float* cw     = (const float*)d_in[8];
  const float* cwa    = (const float*)d_in[9];
  const float* fc_w   = (const float*)d_in[10];
  const float* fc_b   = (const float*)d_in[11];
  const float* emb    = (const float*)d_in[12];
  float* out = (float*)d_out;
  float* ws = (float*)d_ws;
  float* yw   = ws + OFF_YW;
  float* Xs   = ws + OFF_XS;
  float* h    = ws + OFF_H;
  float* hT   = ws + OFF_HT;
  float* Wh1  = ws + OFF_WH1;
  float* Wh2  = ws + OFF_WH2;
  float* adj  = ws + OFF_ADJ;
  float* memT = ws + OFF_MEMT;
  float* WwT  = ws + OFF_WWT;
  float* Mm   = ws + OFF_M;
  float* PT   = ws + OFF_PT;
  float* pb   = ws + OFF_PB;

  hipLaunchKernelGGL(k_pre1, dim3(384), dim3(256), 0, stream,
                     memory, W_w, conv_w, theta, memT, WwT, Mm);
  hipLaunchKernelGGL(k_pre2, dim3(64), dim3(256), 0, stream, Mm, W_w, W_b, PT, pb);
  hipLaunchKernelGGL(k_yw, dim3(4096), dim3(128), 0, stream, x, PT, pb, yw, Xs);
  hipLaunchKernelGGL(k_h, dim3(512), dim3(256), 0, stream,
                     Xs, WwT, W_b, a_vec, h, hT, Wh1, Wh2);
  hipLaunchKernelGGL(k_adj, dim3(1024), dim3(256), 0, stream,
                     h, hT, memT, Wh1, Wh2, cw, cwa, fc_w, fc_b, adj);
  hipLaunchKernelGGL(k_out, dim3(4096), dim3(128), 0, stream,
                     yw, adj, conv_b, emb, x, out);
}

// Round 2
// 437.996 us; speedup vs baseline: 1.8658x; 1.8658x over previous
//
#include <hip/hip_runtime.h>
#include <cstdint>
#include <cstddef>

// B=8, C=128, N=512, T=64, k_sel = 409
#define KSEL 409u
typedef unsigned short ushort;
typedef short s16x8 __attribute__((ext_vector_type(8)));
typedef float f32x4 __attribute__((ext_vector_type(4)));

union FragU { uint4 u; s16x8 v; };

__device__ __forceinline__ ushort f2bf(float f) {
  union { float f; unsigned u; } x; x.f = f;
  unsigned u = x.u;
  return (ushort)((u + 0x7fffu + ((u >> 16) & 1u)) >> 16);
}

// Workspace layout (float offsets)
#define OFF_YW     0u         // 33554432 bf16 = 16777216 f  yw[b,d,n,t] bf16
#define OFF_XS     16777216u  // 524288   Xs[b,n,c]
#define OFF_H      17301504u  // 524288   h[b,n,c]
#define OFF_HT     17825792u  // 524288   hT[b,c,n]
#define OFF_WH1    18350080u  // 4096
#define OFF_WH2    18354176u  // 4096
#define OFF_ADJ    18358272u  // 2097152  adj fp32 [b,n,m]
#define OFF_ADJT   20455424u  // 2097152 bf16 = 1048576 f  adjT[b,m,n] bf16
#define OFF_MEMT   21504000u  // 65536    memT[c,m]
#define OFF_WWT    21569536u  // 16384    WwT[c',c]
#define OFF_M      21585920u  // 16384    M = conv_w @ theta^T
#define OFF_PB16   21602304u  // 16384 bf16 = 8192 f  Pb[d,c] bf16 (P = M@W_w)
#define OFF_PBIAS  21610496u  // 128      pb = M @ W_b

// ---------------- pre-kernels ----------------
__global__ __launch_bounds__(256) void k_pre1(
    const float* __restrict__ memory, const float* __restrict__ W_w,
    const float* __restrict__ conv_w, const float* __restrict__ theta,
    float* __restrict__ memT, float* __restrict__ WwT, float* __restrict__ Mm) {
  int idx = blockIdx.x * 256 + threadIdx.x;
  if (idx < 65536) {
    int c = idx >> 9, m = idx & 511;
    memT[idx] = memory[m * 128 + c];
  } else if (idx < 81920) {
    int i2 = idx - 65536;
    int cp = i2 >> 7, c = i2 & 127;
    WwT[i2] = W_w[c * 128 + cp];
  } else if (idx < 98304) {
    int i3 = idx - 81920;
    int d = i3 >> 7, e = i3 & 127;
    float s = 0.f;
    for (int c = 0; c < 128; ++c) s += conv_w[d * 128 + c] * theta[e * 128 + c];
    Mm[i3] = s;
  }
}

__global__ __launch_bounds__(256) void k_pre2(
    const float* __restrict__ Mm, const float* __restrict__ W_w,
    const float* __restrict__ W_b, ushort* __restrict__ Pb, float* __restrict__ pbias) {
  int idx = blockIdx.x * 256 + threadIdx.x;
  if (idx < 16384) {
    int d = idx >> 7, c = idx & 127;
    float s = 0.f;
    for (int e = 0; e < 128; ++e) s += Mm[d * 128 + e] * W_w[e * 128 + c];
    Pb[d * 128 + c] = f2bf(s);
    if (idx < 128) {
      float s2 = 0.f;
      for (int e = 0; e < 128; ++e) s2 += Mm[idx * 128 + e] * W_b[e];
      pbias[idx] = s2;
    }
  }
}

// ---------------- k_yw (MFMA): yw[b,d,n,t] = bf16( sum_c P[d,c]*x[b,c,n,t] + pb[d] ) ----
// block per (b,n), 256 threads = 4 waves; wave w owns t-tile w. Also emits Xs[b,n,c]=sum_t x.
#define XB_STRIDE 138   // ushort units (276 B)
#define PB_STRIDE 136   // ushort units (272 B)
#define OUT_STRIDE 68   // ushort units (136 B)
__global__ __launch_bounds__(256, 4) void k_yw(
    const float* __restrict__ x, const ushort* __restrict__ Pbg,
    const float* __restrict__ pbias, ushort* __restrict__ ywg, float* __restrict__ Xs) {
  __shared__ __align__(16) ushort pbl[128 * PB_STRIDE];   // 34816 B
  __shared__ __align__(16) ushort xbuf[64 * XB_STRIDE];   // 17664 B (reused for output bounce)
  __shared__ float pbias_sh[128];
  int bid = blockIdx.x;
  int b = bid >> 9, n = bid & 511;
  int tid = threadIdx.x;
  int lane = tid & 63, w = tid >> 6;
  int quad = lane >> 4, lx = lane & 15;

  // stage Pb -> LDS (b128 writes)
  for (int k = 0; k < 8; ++k) {
    int flat8 = tid + 256 * k;
    int d = flat8 >> 4, cseg = flat8 & 15;
    uint4 v = *(const uint4*)(Pbg + d * 128 + cseg * 8);
    *(uint4*)&pbl[d * PB_STRIDE + cseg * 8] = v;
  }
  if (tid < 128) pbias_sh[tid] = pbias[tid];

  // stage x[c 128][t 64] -> xbuf[t][c] (bf16, transposed), plus Xs partial sums
  const float* xbase = x + (size_t)b * 4194304 + (size_t)n * 64;
  for (int k = 0; k < 8; ++k) {
    int c = (tid >> 4) + 16 * k;
    int t0 = (tid & 15) * 4;
    float4 v = *(const float4*)(xbase + (size_t)c * 32768 + t0);
    xbuf[(t0 + 0) * XB_STRIDE + c] = f2bf(v.x);
    xbuf[(t0 + 1) * XB_STRIDE + c] = f2bf(v.y);
    xbuf[(t0 + 2) * XB_STRIDE + c] = f2bf(v.z);
    xbuf[(t0 + 3) * XB_STRIDE + c] = f2bf(v.w);
    float s = v.x + v.y + v.z + v.w;
    s += __shfl_xor(s, 1, 64);
    s += __shfl_xor(s, 2, 64);
    s += __shfl_xor(s, 4, 64);
    s += __shfl_xor(s, 8, 64);
    if ((tid & 15) == 0) Xs[((size_t)(b * 512 + n)) * 128 + c] = s;
  }
  __syncthreads();

  // MFMA: C[d 128][t' 16 per wave], K = c = 128 in 4 chunks of 32
  f32x4 acc[8];
  #pragma unroll
  for (int i = 0; i < 8; ++i) acc[i] = (f32x4){0.f, 0.f, 0.f, 0.f};
  int tp = lx + 16 * w;
  const unsigned* xb32 = (const unsigned*)xbuf;
  #pragma unroll
  for (int kc = 0; kc < 4; ++kc) {
    FragU bf;
    int bbase = tp * (XB_STRIDE / 2) + kc * 16 + quad * 4;
    bf.u.x = xb32[bbase + 0];
    bf.u.y = xb32[bbase + 1];
    bf.u.z = xb32[bbase + 2];
    bf.u.w = xb32[bbase + 3];
    #pragma unroll
    for (int dt = 0; dt < 8; ++dt) {
      FragU af;
      af.u = *(const uint4*)&pbl[(16 * dt + lx) * PB_STRIDE + kc * 32 + quad * 8];
      acc[dt] = __builtin_amdgcn_mfma_f32_16x16x32_bf16(af.v, bf.v, acc[dt], 0, 0, 0);
    }
  }
  __syncthreads();
  // epilogue: acc -> xbuf (stride OUT_STRIDE) with bias
  #pragma unroll
  for (int dt = 0; dt < 8; ++dt)
    #pragma unroll
    for (int r = 0; r < 4; ++r) {
      int d = 16 * dt + quad * 4 + r;
      xbuf[d * OUT_STRIDE + tp] = f2bf(acc[dt][r] + pbias_sh[d]);
    }
  __syncthreads();
  // coalesced bf16 store: yw[b,d,n,t]
  for (int k = 0; k < 4; ++k) {
    int flat8 = tid + 256 * k;
    int d = flat8 >> 3, t0 = (flat8 & 7) * 8;
    ushort4 u0 = *(const ushort4*)&xbuf[d * OUT_STRIDE + t0];
    ushort4 u1 = *(const ushort4*)&xbuf[d * OUT_STRIDE + t0 + 4];
    ushort* dst = ywg + (((size_t)(b * 128 + d)) * 512 + n) * 64 + t0;
    uint4 pk;
    pk.x = (unsigned)u0.x | ((unsigned)u0.y << 16);
    pk.y = (unsigned)u0.z | ((unsigned)u0.w << 16);
    pk.z = (unsigned)u1.x | ((unsigned)u1.y << 16);
    pk.w = (unsigned)u1.z | ((unsigned)u1.w << 16);
    *(uint4*)dst = pk;
  }
}

// ---------------- k_h (unchanged) ----------------
__global__ __launch_bounds__(256) void k_h(
    const float* __restrict__ Xs, const float* __restrict__ WwT,
    const float* __restrict__ W_b, const float* __restrict__ a_vec,
    float* __restrict__ h, float* __restrict__ hT,
    float* __restrict__ Wh1, float* __restrict__ Wh2) {
  __shared__ float wt[64 * 128];
  __shared__ float xs[8 * 128];
  __shared__ float hr[8 * 128];
  __shared__ float av[256];
  int tid = threadIdx.x;
  int row0 = blockIdx.x * 8;
  for (int i = tid; i < 1024; i += 256) xs[i] = Xs[(size_t)row0 * 128 + i];
  av[tid] = a_vec[tid];
  int c = tid & 127;
  int r0 = tid >> 7;
  float wb = W_b[c] * 64.f;
  float acc[4];
  #pragma unroll
  for (int k = 0; k < 4; ++k) acc[k] = wb;
  for (int ch = 0; ch < 2; ++ch) {
    int cp0 = ch * 64;
    __syncthreads();
    for (int i = tid; i < 8192; i += 256) wt[i] = WwT[(size_t)cp0 * 128 + i];
    __syncthreads();
    for (int cpl = 0; cpl < 64; ++cpl) {
      float w = wt[cpl * 128 + c];
      #pragma unroll
      for (int k = 0; k < 4; ++k) acc[k] += xs[(r0 + 2 * k) * 128 + cp0 + cpl] * w;
    }
  }
  #pragma unroll
  for (int k = 0; k < 4; ++k) {
    int r = r0 + 2 * k;
    int rowg = row0 + r;
    int b = rowg >> 9, n = rowg & 511;
    h[(size_t)rowg * 128 + c] = acc[k];
    hT[((size_t)(b * 128 + c)) * 512 + n] = acc[k];
    hr[r * 128 + c] = acc[k];
  }
  __syncthreads();
  if (tid < 8) {
    float w1 = 0.f, w2 = 0.f;
    for (int cc = 0; cc < 128; ++cc) {
      float hv = hr[tid * 128 + cc];
      w1 += hv * av[cc];
      w2 += hv * av[128 + cc];
    }
    Wh1[row0 + tid] = w1;
    Wh2[row0 + tid] = w2;
  }
}

// ---------------- adjacency helpers (unchanged) ----------------
__device__ __forceinline__ void reduce_rows4(float v[4], float* sred, int tid, bool domax) {
  int lane = tid & 63, wid = tid >> 6;
  #pragma unroll
  for (int off = 32; off > 0; off >>= 1) {
    #pragma unroll
    for (int r = 0; r < 4; ++r) {
      float o = __shfl_down(v[r], off, 64);
      v[r] = domax ? fmaxf(v[r], o) : (v[r] + o);
    }
  }
  if (lane == 0) {
    #pragma unroll
    for (int r = 0; r < 4; ++r) sred[r * 4 + wid] = v[r];
  }
  __syncthreads();
  #pragma unroll
  for (int r = 0; r < 4; ++r) {
    float a0 = sred[r * 4 + 0], a1 = sred[r * 4 + 1];
    float a2 = sred[r * 4 + 2], a3 = sred[r * 4 + 3];
    v[r] = domax ? fmaxf(fmaxf(a0, a1), fmaxf(a2, a3)) : (a0 + a1 + a2 + a3);
  }
  __syncthreads();
}

__device__ __forceinline__ void softmax_rows4(float v[4][2], float* sred, int tid) {
  float mx[4];
  #pragma unroll
  for (int r = 0; r < 4; ++r) mx[r] = fmaxf(v[r][0], v[r][1]);
  reduce_rows4(mx, sred, tid, true);
  float sm[4];
  #pragma unroll
  for (int r = 0; r < 4; ++r) {
    v[r][0] = expf(v[r][0] - mx[r]);
    v[r][1] = expf(v[r][1] - mx[r]);
    sm[r] = v[r][0] + v[r][1];
  }
  reduce_rows4(sm, sred, tid, false);
  #pragma unroll
  for (int r = 0; r < 4; ++r) {
    float inv = 1.f / sm[r];
    v[r][0] *= inv;
    v[r][1] *= inv;
  }
}

// ---------------- k_adj (unchanged) ----------------
__global__ __launch_bounds__(256) void k_adj(
    const float* __restrict__ h, const float* __restrict__ hT,
    const float* __restrict__ memT, const float* __restrict__ Wh1,
    const float* __restrict__ Wh2, const float* __restrict__ cw,
    const float* __restrict__ cwa, const float* __restrict__ fc_w,
    const float* __restrict__ fc_b, float* __restrict__ adj) {
  __shared__ float hn[4 * 128];
  __shared__ float sred[16];
  __shared__ unsigned scnt[124];
  int tid = threadIdx.x;
  int b = blockIdx.x >> 7;
  int n0 = (blockIdx.x & 127) * 4;
  for (int i = tid; i < 512; i += 256) hn[i] = h[((size_t)(b * 512 + n0)) * 128 + i];
  for (int i = tid; i < 124; i += 256) scnt[i] = 0u;
  __syncthreads();
  int m0 = tid, m1 = tid + 256;
  float d1[4][2] = {}, d2[4][2] = {};
  for (int c = 0; c < 128; ++c) {
    float mv0 = memT[c * 512 + m0];
    float mv1 = memT[c * 512 + m1];
    const float* hTr = hT + ((size_t)(b * 128 + c)) * 512;
    float hv0 = hTr[m0];
    float hv1 = hTr[m1];
    #pragma unroll
    for (int r = 0; r < 4; ++r) {
      float hc = hn[r * 128 + c];
      d1[r][0] += hc * mv0; d1[r][1] += hc * mv1;
      d2[r][0] += hc * hv0; d2[r][1] += hc * hv1;
    }
  }
  const float scale = 0.08838834764831845f;
  float l1[4][2], l2[4][2];
  #pragma unroll
  for (int r = 0; r < 4; ++r)
    #pragma unroll
    for (int s = 0; s < 2; ++s) {
      l1[r][s] = fmaxf(d1[r][s] * scale, 0.f);
      l2[r][s] = fmaxf(d2[r][s] * scale, 0.f);
    }
  softmax_rows4(l1, sred, tid);
  softmax_rows4(l2, sred, tid);
  float f0 = fc_w[0], f1 = fc_w[1], fb = fc_b[0];
  float wh2v[2] = {Wh2[b * 512 + m0], Wh2[b * 512 + m1]};
  float aw[4][2];
  #pragma unroll
  for (int r = 0; r < 4; ++r) {
    int n = n0 + r;
    float wh1v = Wh1[b * 512 + n];
    #pragma unroll
    for (int s = 0; s < 2; ++s) {
      int m = s ? m1 : m0;
      float e = wh1v + wh2v[s];
      float adjf = f0 * l1[r][s] + f1 * l2[r][s] + fb;
      aw[r][s] = e * cw[n * 512 + m] + adjf * cwa[n * 512 + m];
    }
  }
  softmax_rows4(aw, sred, tid);
  unsigned ua[4][2];
  #pragma unroll
  for (int r = 0; r < 4; ++r) {
    ua[r][0] = __float_as_uint(aw[r][0]);
    ua[r][1] = __float_as_uint(aw[r][1]);
  }
  unsigned cand[4] = {0u, 0u, 0u, 0u};
  int lane = tid & 63;
  for (int bit = 30; bit >= 0; --bit) {
    unsigned msk = 1u << bit;
    #pragma unroll
    for (int r = 0; r < 4; ++r) {
      unsigned tst = cand[r] | msk;
      unsigned long long b0 = __ballot(ua[r][0] >= tst);
      unsigned long long b1 = __ballot(ua[r][1] >= tst);
      if (lane == 0)
        atomicAdd(&scnt[bit * 4 + r], (unsigned)(__popcll(b0) + __popcll(b1)));
    }
    __syncthreads();
    #pragma unroll
    for (int r = 0; r < 4; ++r)
      if (scnt[bit * 4 + r] >= KSEL) cand[r] |= msk;
  }
  #pragma unroll
  for (int r = 0; r < 4; ++r) {
    size_t base = ((size_t)(b * 512 + n0 + r)) * 512;
    adj[base + m0] = (ua[r][0] >= cand[r]) ? aw[r][0] : 0.f;
    adj[base + m1] = (ua[r][1] >= cand[r]) ? aw[r][1] : 0.f;
  }
}

// ---------------- k_adjT: adj fp32 [b,n,m] -> adjT bf16 [b,m,n] ----------------
__global__ __launch_bounds__(256) void k_adjT(
    const float* __restrict__ adj, ushort* __restrict__ adjT) {
  __shared__ float tile[32][33];
  int gid = blockIdx.x;
  int b = gid >> 8;
  int tn = (gid & 255) >> 4, tm = gid & 15;
  int n0 = tn * 32, m0 = tm * 32;
  int tid = threadIdx.x;
  int nl = tid >> 3, ms = (tid & 7) * 4;
  float4 v = *(const float4*)(adj + (size_t)b * 262144 + (size_t)(n0 + nl) * 512 + m0 + ms);
  tile[nl][ms + 0] = v.x; tile[nl][ms + 1] = v.y;
  tile[nl][ms + 2] = v.z; tile[nl][ms + 3] = v.w;
  __syncthreads();
  int ml = tid >> 3, ns = (tid & 7) * 4;
  ushort4 o;
  o.x = f2bf(tile[ns + 0][ml]);
  o.y = f2bf(tile[ns + 1][ml]);
  o.z = f2bf(tile[ns + 2][ml]);
  o.w = f2bf(tile[ns + 3][ml]);
  *(ushort4*)(adjT + (size_t)b * 262144 + (size_t)(m0 + ml) * 512 + n0 + ns) = o;
}

// ---------------- k_out (MFMA): out[b,d,m,t] = (cb[d] + sum_n adjT[b,m,n]*yw[b,d,n,t])*emb[d,m] + x ----
// block per (b,d), 512 threads = 8 waves; wave w owns m 64w..64w+63; C[m 512][t 64].
#define AJ_STRIDE 40   // ushort (80 B)
#define YB_STRIDE 82   // ushort (164 B)
__global__ __launch_bounds__(512, 4) void k_out(
    const ushort* __restrict__ ywg, const ushort* __restrict__ adjT,
    const float* __restrict__ conv_b, const float* __restrict__ emb,
    const float* __restrict__ x, float* __restrict__ out) {
  __shared__ __align__(16) ushort adjt[512 * AJ_STRIDE];  // 40960 B
  __shared__ __align__(16) ushort ywb[64 * YB_STRIDE];    // 10496 B
  __shared__ float semb[512];
  int gid = blockIdx.x;
  int b = gid >> 7, d = gid & 127;
  int tid = threadIdx.x;
  int lane = tid & 63, w = tid >> 6;
  int quad = lane >> 4, lx = lane & 15;
  for (int i = tid; i < 512; i += 512) semb[i] = emb[d * 512 + i];
  float cb = conv_b[d];
  const ushort* adjTb = adjT + (size_t)b * 262144;
  const ushort* ywbase = ywg + ((size_t)(b * 128 + d)) * 32768;
  f32x4 acc[4][4];
  #pragma unroll
  for (int i = 0; i < 4; ++i)
    #pragma unroll
    for (int j = 0; j < 4; ++j) acc[i][j] = (f32x4){0.f, 0.f, 0.f, 0.f};
  const unsigned* ywb32 = (const unsigned*)ywb;

  for (int nc = 0; nc < 16; ++nc) {
    if (nc) __syncthreads();
    // stage adjT chunk [m 512][n 32] -> adjt (b128)
    {
      int ml = tid >> 2, seg = tid & 3;
      #pragma unroll
      for (int kk = 0; kk < 4; ++kk) {
        int m = ml + 128 * kk;
        uint4 v = *(const uint4*)(adjTb + (size_t)m * 512 + nc * 32 + seg * 8);
        *(uint4*)&adjt[m * AJ_STRIDE + seg * 8] = v;
      }
    }
    // stage yw chunk [n 32][t 64] -> ywb[t][n] (transpose, scalar b16)
    {
      int t = tid & 63, nl = tid >> 6;
      #pragma unroll
      for (int kk = 0; kk < 4; ++kk) {
        int n_loc = nl + 8 * kk;
        ushort v = ywbase[(size_t)(nc * 32 + n_loc) * 64 + t];
        ywb[t * YB_STRIDE + n_loc] = v;
      }
    }
    __syncthreads();
    // B-frags per tt, A-frags per mt
    FragU bf[4];
    #pragma unroll
    for (int tt = 0; tt < 4; ++tt) {
      int t = lx + 16 * tt;
      int bb = t * (YB_STRIDE / 2) + quad * 4;
      bf[tt].u.x = ywb32[bb + 0];
      bf[tt].u.y = ywb32[bb + 1];
      bf[tt].u.z = ywb32[bb + 2];
      bf[tt].u.w = ywb32[bb + 3];
    }
    #pragma unroll
    for (int mt = 0; mt < 4; ++mt) {
      int m = 64 * w + 16 * mt + lx;
      FragU af;
      af.u = *(const uint4*)&adjt[m * AJ_STRIDE + quad * 8];
      #pragma unroll
      for (int tt = 0; tt < 4; ++tt)
        acc[mt][tt] = __builtin_amdgcn_mfma_f32_16x16x32_bf16(af.v, bf[tt].v, acc[mt][tt], 0, 0, 0);
    }
  }
  // epilogue: (acc + cb) * emb[d,m] + x, fp32 stores
  size_t obase = ((size_t)(b * 128 + d)) * 32768;
  #pragma unroll
  for (int mt = 0; mt < 4; ++mt) {
    #pragma unroll
    for (int r = 0; r < 4; ++r) {
      int m = 64 * w + 16 * mt + quad * 4 + r;
      float em = semb[m];
      #pragma unroll
      for (int tt = 0; tt < 4; ++tt) {
        int t = lx + 16 * tt;
        size_t idx = obase + (size_t)m * 64 + t;
        out[idx] = (acc[mt][tt][r] + cb) * em + x[idx];
      }
    }
  }
}

extern "C" void kernel_launch(void* const* d_in, const int* in_sizes, int n_in,
                              void* d_out, int out_size, void* d_ws, size_t ws_size,
                              hipStream_t stream) {
  const float* x      = (const float*)d_in[0];
  const float* W_w    = (const float*)d_in[1];
  const float* W_b    = (const float*)d_in[2];
  const float* conv_w = (const float*)d_in[3];
  const float* conv_b = (const float*)d_in[4];
  const float* theta  = (const float*)d_in[5];
  const float* memory = (const float*)d_in[6];
  const float* a_vec  = (const float*)d_in[7];
  const float* cw     = (const float*)d_in[8];
  const float* cwa    = (const float*)d_in[9];
  const float* fc_w   = (const float*)d_in[10];
  const float* fc_b   = (const float*)d_in[11];
  const float* emb    = (const float*)d_in[12];
  float* out = (float*)d_out;
  float* ws = (float*)d_ws;
  ushort* ywbf  = (ushort*)(ws + OFF_YW);
  float* Xs     = ws + OFF_XS;
  float* h      = ws + OFF_H;
  float* hT     = ws + OFF_HT;
  float* Wh1    = ws + OFF_WH1;
  float* Wh2    = ws + OFF_WH2;
  float* adj    = ws + OFF_ADJ;
  ushort* adjT  = (ushort*)(ws + OFF_ADJT);
  float* memT   = ws + OFF_MEMT;
  float* WwT    = ws + OFF_WWT;
  float* Mm     = ws + OFF_M;
  ushort* Pb    = (ushort*)(ws + OFF_PB16);
  float* pbias  = ws + OFF_PBIAS;

  hipLaunchKernelGGL(k_pre1, dim3(384), dim3(256), 0, stream,
                     memory, W_w, conv_w, theta, memT, WwT, Mm);
  hipLaunchKernelGGL(k_pre2, dim3(64), dim3(256), 0, stream, Mm, W_w, W_b, Pb, pbias);
  hipLaunchKernelGGL(k_yw, dim3(4096), dim3(256), 0, stream, x, Pb, pbias, ywbf, Xs);
  hipLaunchKernelGGL(k_h, dim3(512), dim3(256), 0, stream,
                     Xs, WwT, W_b, a_vec, h, hT, Wh1, Wh2);
  hipLaunchKernelGGL(k_adj, dim3(1024), dim3(256), 0, stream,
                     h, hT, memT, Wh1, Wh2, cw, cwa, fc_w, fc_b, adj);
  hipLaunchKernelGGL(k_adjT, dim3(2048), dim3(256), 0, stream, adj, adjT);
  hipLaunchKernelGGL(k_out, dim3(1024), dim3(512), 0, stream,
                     ywbf, adjT, conv_b, emb, x, out);
}

// Round 3
// 431.952 us; speedup vs baseline: 1.8919x; 1.0140x over previous
//
#include <hip/hip_runtime.h>
#include <cstdint>
#include <cstddef>

// B=8, C=128, N=512, T=64, k_sel = 409
#define KSEL 409u
typedef unsigned short ushort;
typedef short s16x8 __attribute__((ext_vector_type(8)));
typedef float f32x4 __attribute__((ext_vector_type(4)));

union FragU { uint4 u; s16x8 v; };

__device__ __forceinline__ ushort f2bf(float f) {
  union { float f; unsigned u; } x; x.f = f;
  unsigned u = x.u;
  return (ushort)((u + 0x7fffu + ((u >> 16) & 1u)) >> 16);
}

// Workspace layout (float offsets)
#define OFF_YW     0u         // 33554432 bf16 = 16777216 f  yw[b,d,n,t] bf16
#define OFF_XS     16777216u  // 524288   Xs[b,n,c]
#define OFF_H      17301504u  // 524288   h[b,n,c]
#define OFF_HT     17825792u  // 524288   hT[b,c,n]
#define OFF_WH1    18350080u  // 4096
#define OFF_WH2    18354176u  // 4096
#define OFF_ADJT   18358272u  // 2097152 bf16 = 1048576 f  adjT[b,m,n] bf16
#define OFF_MEMT   19406848u  // 65536    memT[c,m]
#define OFF_WWT    19472384u  // 16384    WwT[c',c]
#define OFF_M      19488768u  // 16384    M = conv_w @ theta^T
#define OFF_PB16   19505152u  // 16384 bf16 = 8192 f  Pb[d,c] bf16 (P = M@W_w)
#define OFF_PBIAS  19513344u  // 128      pb = M @ W_b

// ---------------- pre-kernels ----------------
__global__ __launch_bounds__(256) void k_pre1(
    const float* __restrict__ memory, const float* __restrict__ W_w,
    const float* __restrict__ conv_w, const float* __restrict__ theta,
    float* __restrict__ memT, float* __restrict__ WwT, float* __restrict__ Mm) {
  int idx = blockIdx.x * 256 + threadIdx.x;
  if (idx < 65536) {
    int c = idx >> 9, m = idx & 511;
    memT[idx] = memory[m * 128 + c];
  } else if (idx < 81920) {
    int i2 = idx - 65536;
    int cp = i2 >> 7, c = i2 & 127;
    WwT[i2] = W_w[c * 128 + cp];
  } else if (idx < 98304) {
    int i3 = idx - 81920;
    int d = i3 >> 7, e = i3 & 127;
    float s = 0.f;
    for (int c = 0; c < 128; ++c) s += conv_w[d * 128 + c] * theta[e * 128 + c];
    Mm[i3] = s;
  }
}

__global__ __launch_bounds__(256) void k_pre2(
    const float* __restrict__ Mm, const float* __restrict__ W_w,
    const float* __restrict__ W_b, ushort* __restrict__ Pb, float* __restrict__ pbias) {
  int idx = blockIdx.x * 256 + threadIdx.x;
  if (idx < 16384) {
    int d = idx >> 7, c = idx & 127;
    float s = 0.f;
    for (int e = 0; e < 128; ++e) s += Mm[d * 128 + e] * W_w[e * 128 + c];
    Pb[d * 128 + c] = f2bf(s);
    if (idx < 128) {
      float s2 = 0.f;
      for (int e = 0; e < 128; ++e) s2 += Mm[idx * 128 + e] * W_b[e];
      pbias[idx] = s2;
    }
  }
}

// ---------------- k_yw (MFMA): yw[b,d,n,t] = bf16( sum_c P[d,c]*x[b,c,n,t] + pb[d] ) ----
#define XB_STRIDE 138
#define PB_STRIDE 136
#define OUT_STRIDE 68
__global__ __launch_bounds__(256, 4) void k_yw(
    const float* __restrict__ x, const ushort* __restrict__ Pbg,
    const float* __restrict__ pbias, ushort* __restrict__ ywg, float* __restrict__ Xs) {
  __shared__ __align__(16) ushort pbl[128 * PB_STRIDE];
  __shared__ __align__(16) ushort xbuf[64 * XB_STRIDE];
  __shared__ float pbias_sh[128];
  int bid = blockIdx.x;
  int b = bid >> 9, n = bid & 511;
  int tid = threadIdx.x;
  int lane = tid & 63, w = tid >> 6;
  int quad = lane >> 4, lx = lane & 15;

  for (int k = 0; k < 8; ++k) {
    int flat8 = tid + 256 * k;
    int d = flat8 >> 4, cseg = flat8 & 15;
    uint4 v = *(const uint4*)(Pbg + d * 128 + cseg * 8);
    *(uint4*)&pbl[d * PB_STRIDE + cseg * 8] = v;
  }
  if (tid < 128) pbias_sh[tid] = pbias[tid];

  const float* xbase = x + (size_t)b * 4194304 + (size_t)n * 64;
  for (int k = 0; k < 8; ++k) {
    int c = (tid >> 4) + 16 * k;
    int t0 = (tid & 15) * 4;
    float4 v = *(const float4*)(xbase + (size_t)c * 32768 + t0);
    xbuf[(t0 + 0) * XB_STRIDE + c] = f2bf(v.x);
    xbuf[(t0 + 1) * XB_STRIDE + c] = f2bf(v.y);
    xbuf[(t0 + 2) * XB_STRIDE + c] = f2bf(v.z);
    xbuf[(t0 + 3) * XB_STRIDE + c] = f2bf(v.w);
    float s = v.x + v.y + v.z + v.w;
    s += __shfl_xor(s, 1, 64);
    s += __shfl_xor(s, 2, 64);
    s += __shfl_xor(s, 4, 64);
    s += __shfl_xor(s, 8, 64);
    if ((tid & 15) == 0) Xs[((size_t)(b * 512 + n)) * 128 + c] = s;
  }
  __syncthreads();

  f32x4 acc[8];
  #pragma unroll
  for (int i = 0; i < 8; ++i) acc[i] = (f32x4){0.f, 0.f, 0.f, 0.f};
  int tp = lx + 16 * w;
  const unsigned* xb32 = (const unsigned*)xbuf;
  #pragma unroll
  for (int kc = 0; kc < 4; ++kc) {
    FragU bf;
    int bbase = tp * (XB_STRIDE / 2) + kc * 16 + quad * 4;
    bf.u.x = xb32[bbase + 0];
    bf.u.y = xb32[bbase + 1];
    bf.u.z = xb32[bbase + 2];
    bf.u.w = xb32[bbase + 3];
    #pragma unroll
    for (int dt = 0; dt < 8; ++dt) {
      FragU af;
      af.u = *(const uint4*)&pbl[(16 * dt + lx) * PB_STRIDE + kc * 32 + quad * 8];
      acc[dt] = __builtin_amdgcn_mfma_f32_16x16x32_bf16(af.v, bf.v, acc[dt], 0, 0, 0);
    }
  }
  __syncthreads();
  #pragma unroll
  for (int dt = 0; dt < 8; ++dt)
    #pragma unroll
    for (int r = 0; r < 4; ++r) {
      int d = 16 * dt + quad * 4 + r;
      xbuf[d * OUT_STRIDE + tp] = f2bf(acc[dt][r] + pbias_sh[d]);
    }
  __syncthreads();
  for (int k = 0; k < 4; ++k) {
    int flat8 = tid + 256 * k;
    int d = flat8 >> 3, t0 = (flat8 & 7) * 8;
    ushort4 u0 = *(const ushort4*)&xbuf[d * OUT_STRIDE + t0];
    ushort4 u1 = *(const ushort4*)&xbuf[d * OUT_STRIDE + t0 + 4];
    ushort* dst = ywg + (((size_t)(b * 128 + d)) * 512 + n) * 64 + t0;
    uint4 pk;
    pk.x = (unsigned)u0.x | ((unsigned)u0.y << 16);
    pk.y = (unsigned)u0.z | ((unsigned)u0.w << 16);
    pk.z = (unsigned)u1.x | ((unsigned)u1.y << 16);
    pk.w = (unsigned)u1.z | ((unsigned)u1.w << 16);
    *(uint4*)dst = pk;
  }
}

// ---------------- k_h ----------------
__global__ __launch_bounds__(256) void k_h(
    const float* __restrict__ Xs, const float* __restrict__ WwT,
    const float* __restrict__ W_b, const float* __restrict__ a_vec,
    float* __restrict__ h, float* __restrict__ hT,
    float* __restrict__ Wh1, float* __restrict__ Wh2) {
  __shared__ float wt[64 * 128];
  __shared__ float xs[8 * 128];
  __shared__ float hr[8 * 128];
  __shared__ float av[256];
  int tid = threadIdx.x;
  int row0 = blockIdx.x * 8;
  for (int i = tid; i < 1024; i += 256) xs[i] = Xs[(size_t)row0 * 128 + i];
  av[tid] = a_vec[tid];
  int c = tid & 127;
  int r0 = tid >> 7;
  float wb = W_b[c] * 64.f;
  float acc[4];
  #pragma unroll
  for (int k = 0; k < 4; ++k) acc[k] = wb;
  for (int ch = 0; ch < 2; ++ch) {
    int cp0 = ch * 64;
    __syncthreads();
    for (int i = tid; i < 8192; i += 256) wt[i] = WwT[(size_t)cp0 * 128 + i];
    __syncthreads();
    for (int cpl = 0; cpl < 64; ++cpl) {
      float w = wt[cpl * 128 + c];
      #pragma unroll
      for (int k = 0; k < 4; ++k) acc[k] += xs[(r0 + 2 * k) * 128 + cp0 + cpl] * w;
    }
  }
  #pragma unroll
  for (int k = 0; k < 4; ++k) {
    int r = r0 + 2 * k;
    int rowg = row0 + r;
    int b = rowg >> 9, n = rowg & 511;
    h[(size_t)rowg * 128 + c] = acc[k];
    hT[((size_t)(b * 128 + c)) * 512 + n] = acc[k];
    hr[r * 128 + c] = acc[k];
  }
  __syncthreads();
  if (tid < 8) {
    float w1 = 0.f, w2 = 0.f;
    for (int cc = 0; cc < 128; ++cc) {
      float hv = hr[tid * 128 + cc];
      w1 += hv * av[cc];
      w2 += hv * av[128 + cc];
    }
    Wh1[row0 + tid] = w1;
    Wh2[row0 + tid] = w2;
  }
}

// ---------------- adjacency helpers ----------------
__device__ __forceinline__ void reduce_rows4(float v[4], float* sred, int tid, bool domax) {
  int lane = tid & 63, wid = tid >> 6;
  #pragma unroll
  for (int off = 32; off > 0; off >>= 1) {
    #pragma unroll
    for (int r = 0; r < 4; ++r) {
      float o = __shfl_down(v[r], off, 64);
      v[r] = domax ? fmaxf(v[r], o) : (v[r] + o);
    }
  }
  if (lane == 0) {
    #pragma unroll
    for (int r = 0; r < 4; ++r) sred[r * 4 + wid] = v[r];
  }
  __syncthreads();
  #pragma unroll
  for (int r = 0; r < 4; ++r) {
    float a0 = sred[r * 4 + 0], a1 = sred[r * 4 + 1];
    float a2 = sred[r * 4 + 2], a3 = sred[r * 4 + 3];
    v[r] = domax ? fmaxf(fmaxf(a0, a1), fmaxf(a2, a3)) : (a0 + a1 + a2 + a3);
  }
  __syncthreads();
}

__device__ __forceinline__ void softmax_rows4(float v[4][2], float* sred, int tid) {
  float mx[4];
  #pragma unroll
  for (int r = 0; r < 4; ++r) mx[r] = fmaxf(v[r][0], v[r][1]);
  reduce_rows4(mx, sred, tid, true);
  float sm[4];
  #pragma unroll
  for (int r = 0; r < 4; ++r) {
    v[r][0] = expf(v[r][0] - mx[r]);
    v[r][1] = expf(v[r][1] - mx[r]);
    sm[r] = v[r][0] + v[r][1];
  }
  reduce_rows4(sm, sred, tid, false);
  #pragma unroll
  for (int r = 0; r < 4; ++r) {
    float inv = 1.f / sm[r];
    v[r][0] *= inv;
    v[r][1] *= inv;
  }
}

// ---------------- k_adj: adjacency + softmaxes + top-409; writes adjT bf16 [b,m,n] directly ----
__global__ __launch_bounds__(256) void k_adj(
    const float* __restrict__ h, const float* __restrict__ hT,
    const float* __restrict__ memT, const float* __restrict__ Wh1,
    const float* __restrict__ Wh2, const float* __restrict__ cw,
    const float* __restrict__ cwa, const float* __restrict__ fc_w,
    const float* __restrict__ fc_b, ushort* __restrict__ adjT) {
  __shared__ float hn[4 * 128];
  __shared__ float sred[16];
  __shared__ unsigned scnt[124];
  int tid = threadIdx.x;
  int b = blockIdx.x >> 7;
  int n0 = (blockIdx.x & 127) * 4;
  for (int i = tid; i < 512; i += 256) hn[i] = h[((size_t)(b * 512 + n0)) * 128 + i];
  for (int i = tid; i < 124; i += 256) scnt[i] = 0u;
  __syncthreads();
  int m0 = tid, m1 = tid + 256;
  float d1[4][2] = {}, d2[4][2] = {};
  for (int c = 0; c < 128; ++c) {
    float mv0 = memT[c * 512 + m0];
    float mv1 = memT[c * 512 + m1];
    const float* hTr = hT + ((size_t)(b * 128 + c)) * 512;
    float hv0 = hTr[m0];
    float hv1 = hTr[m1];
    #pragma unroll
    for (int r = 0; r < 4; ++r) {
      float hc = hn[r * 128 + c];
      d1[r][0] += hc * mv0; d1[r][1] += hc * mv1;
      d2[r][0] += hc * hv0; d2[r][1] += hc * hv1;
    }
  }
  const float scale = 0.08838834764831845f;
  float l1[4][2], l2[4][2];
  #pragma unroll
  for (int r = 0; r < 4; ++r)
    #pragma unroll
    for (int s = 0; s < 2; ++s) {
      l1[r][s] = fmaxf(d1[r][s] * scale, 0.f);
      l2[r][s] = fmaxf(d2[r][s] * scale, 0.f);
    }
  softmax_rows4(l1, sred, tid);
  softmax_rows4(l2, sred, tid);
  float f0 = fc_w[0], f1 = fc_w[1], fb = fc_b[0];
  float wh2v[2] = {Wh2[b * 512 + m0], Wh2[b * 512 + m1]};
  float aw[4][2];
  #pragma unroll
  for (int r = 0; r < 4; ++r) {
    int n = n0 + r;
    float wh1v = Wh1[b * 512 + n];
    #pragma unroll
    for (int s = 0; s < 2; ++s) {
      int m = s ? m1 : m0;
      float e = wh1v + wh2v[s];
      float adjf = f0 * l1[r][s] + f1 * l2[r][s] + fb;
      aw[r][s] = e * cw[n * 512 + m] + adjf * cwa[n * 512 + m];
    }
  }
  softmax_rows4(aw, sred, tid);
  unsigned ua[4][2];
  #pragma unroll
  for (int r = 0; r < 4; ++r) {
    ua[r][0] = __float_as_uint(aw[r][0]);
    ua[r][1] = __float_as_uint(aw[r][1]);
  }
  unsigned cand[4] = {0u, 0u, 0u, 0u};
  int lane = tid & 63;
  for (int bit = 30; bit >= 0; --bit) {
    unsigned msk = 1u << bit;
    #pragma unroll
    for (int r = 0; r < 4; ++r) {
      unsigned tst = cand[r] | msk;
      unsigned long long b0 = __ballot(ua[r][0] >= tst);
      unsigned long long b1 = __ballot(ua[r][1] >= tst);
      if (lane == 0)
        atomicAdd(&scnt[bit * 4 + r], (unsigned)(__popcll(b0) + __popcll(b1)));
    }
    __syncthreads();
    #pragma unroll
    for (int r = 0; r < 4; ++r)
      if (scnt[bit * 4 + r] >= KSEL) cand[r] |= msk;
  }
  // write adjT bf16 [b][m][n] directly (scattered 2B, L2-absorbed)
  ushort* adjTb = adjT + (size_t)b * 262144;
  #pragma unroll
  for (int r = 0; r < 4; ++r) {
    int n = n0 + r;
    adjTb[(size_t)m0 * 512 + n] = (ua[r][0] >= cand[r]) ? f2bf(aw[r][0]) : (ushort)0;
    adjTb[(size_t)m1 * 512 + n] = (ua[r][1] >= cand[r]) ? f2bf(aw[r][1]) : (ushort)0;
  }
}

// ---------------- k_out (MFMA, reg-prefetch pipelined) ----------------
// out[b,d,m,t] = (cb[d] + sum_n adjT[b,m,n]*yw[b,d,n,t])*emb[d,m] + x
// block per (b,d), 512 threads = 8 waves; wave w owns m 64w..64w+63; C[m 512][t 64].
#define AJ_STRIDE 40   // ushort (80 B)
#define YB_STRIDE 82   // ushort (164 B)
__global__ __launch_bounds__(512, 4) void k_out(
    const ushort* __restrict__ ywg, const ushort* __restrict__ adjT,
    const float* __restrict__ conv_b, const float* __restrict__ emb,
    const float* __restrict__ x, float* __restrict__ out) {
  __shared__ __align__(16) ushort adjt[512 * AJ_STRIDE];  // 40960 B
  __shared__ __align__(16) ushort ywb[64 * YB_STRIDE];    // 10496 B
  __shared__ float semb[512];
  int gid = blockIdx.x;
  int b = gid >> 7, d = gid & 127;
  int tid = threadIdx.x;
  int lane = tid & 63, w = tid >> 6;
  int quad = lane >> 4, lx = lane & 15;
  semb[tid] = emb[d * 512 + tid];
  float cb = conv_b[d];
  const ushort* adjTb = adjT + (size_t)b * 262144;
  const ushort* ywbase = ywg + ((size_t)(b * 128 + d)) * 32768;
  f32x4 acc[4][4];
  #pragma unroll
  for (int i = 0; i < 4; ++i)
    #pragma unroll
    for (int j = 0; j < 4; ++j) acc[i][j] = (f32x4){0.f, 0.f, 0.f, 0.f};
  const unsigned* ywb32 = (const unsigned*)ywb;

  // prefetch addressing
  int aml = tid >> 2, aseg = tid & 3;
  int yt = tid & 63, ynl = tid >> 6;
  const ushort* aPtr = adjTb + (size_t)aml * 512 + aseg * 8;
  uint4 pa0, pa1, pa2, pa3;
  ushort py0, py1, py2, py3;
#define LOADC(nc) do {                                               \
    pa0 = *(const uint4*)(aPtr + (nc) * 32);                         \
    pa1 = *(const uint4*)(aPtr + 65536 + (nc) * 32);                 \
    pa2 = *(const uint4*)(aPtr + 131072 + (nc) * 32);                \
    pa3 = *(const uint4*)(aPtr + 196608 + (nc) * 32);                \
    py0 = ywbase[(size_t)((nc) * 32 + ynl) * 64 + yt];               \
    py1 = ywbase[(size_t)((nc) * 32 + ynl + 8) * 64 + yt];           \
    py2 = ywbase[(size_t)((nc) * 32 + ynl + 16) * 64 + yt];         \
    py3 = ywbase[(size_t)((nc) * 32 + ynl + 24) * 64 + yt];         \
  } while (0)

  LOADC(0);
  for (int nc = 0; nc < 16; ++nc) {
    __syncthreads();   // prior chunk's frag reads complete
    *(uint4*)&adjt[(aml      ) * AJ_STRIDE + aseg * 8] = pa0;
    *(uint4*)&adjt[(aml + 128) * AJ_STRIDE + aseg * 8] = pa1;
    *(uint4*)&adjt[(aml + 256) * AJ_STRIDE + aseg * 8] = pa2;
    *(uint4*)&adjt[(aml + 384) * AJ_STRIDE + aseg * 8] = pa3;
    ywb[yt * YB_STRIDE + ynl     ] = py0;
    ywb[yt * YB_STRIDE + ynl + 8 ] = py1;
    ywb[yt * YB_STRIDE + ynl + 16] = py2;
    ywb[yt * YB_STRIDE + ynl + 24] = py3;
    __syncthreads();
    if (nc < 15) LOADC(nc + 1);   // next chunk's loads fly during MFMA
    FragU bf[4];
    #pragma unroll
    for (int tt = 0; tt < 4; ++tt) {
      int t = lx + 16 * tt;
      int bb = t * (YB_STRIDE / 2) + quad * 4;
      bf[tt].u.x = ywb32[bb + 0];
      bf[tt].u.y = ywb32[bb + 1];
      bf[tt].u.z = ywb32[bb + 2];
      bf[tt].u.w = ywb32[bb + 3];
    }
    #pragma unroll
    for (int mt = 0; mt < 4; ++mt) {
      int m = 64 * w + 16 * mt + lx;
      FragU af;
      af.u = *(const uint4*)&adjt[m * AJ_STRIDE + quad * 8];
      #pragma unroll
      for (int tt = 0; tt < 4; ++tt)
        acc[mt][tt] = __builtin_amdgcn_mfma_f32_16x16x32_bf16(af.v, bf[tt].v, acc[mt][tt], 0, 0, 0);
    }
  }
#undef LOADC
  // epilogue: (acc + cb) * emb[d,m] + x, fp32 stores
  size_t obase = ((size_t)(b * 128 + d)) * 32768;
  #pragma unroll
  for (int mt = 0; mt < 4; ++mt) {
    #pragma unroll
    for (int r = 0; r < 4; ++r) {
      int m = 64 * w + 16 * mt + quad * 4 + r;
      float em = semb[m];
      #pragma unroll
      for (int tt = 0; tt < 4; ++tt) {
        int t = lx + 16 * tt;
        size_t idx = obase + (size_t)m * 64 + t;
        out[idx] = (acc[mt][tt][r] + cb) * em + x[idx];
      }
    }
  }
}

extern "C" void kernel_launch(void* const* d_in, const int* in_sizes, int n_in,
                              void* d_out, int out_size, void* d_ws, size_t ws_size,
                              hipStream_t stream) {
  const float* x      = (const float*)d_in[0];
  const float* W_w    = (const float*)d_in[1];
  const float* W_b    = (const float*)d_in[2];
  const float* conv_w = (const float*)d_in[3];
  const float* conv_b = (const float*)d_in[4];
  const float* theta  = (const float*)d_in[5];
  const float* memory = (const float*)d_in[6];
  const float* a_vec  = (const float*)d_in[7];
  const float* cw     = (const float*)d_in[8];
  const float* cwa    = (const float*)d_in[9];
  const float* fc_w   = (const float*)d_in[10];
  const float* fc_b   = (const float*)d_in[11];
  const float* emb    = (const float*)d_in[12];
  float* out = (float*)d_out;
  float* ws = (float*)d_ws;
  ushort* ywbf  = (ushort*)(ws + OFF_YW);
  float* Xs     = ws + OFF_XS;
  float* h      = ws + OFF_H;
  float* hT     = ws + OFF_HT;
  float* Wh1    = ws + OFF_WH1;
  float* Wh2    = ws + OFF_WH2;
  ushort* adjT  = (ushort*)(ws + OFF_ADJT);
  float* memT   = ws + OFF_MEMT;
  float* WwT    = ws + OFF_WWT;
  float* Mm     = ws + OFF_M;
  ushort* Pb    = (ushort*)(ws + OFF_PB16);
  float* pbias  = ws + OFF_PBIAS;

  hipLaunchKernelGGL(k_pre1, dim3(384), dim3(256), 0, stream,
                     memory, W_w, conv_w, theta, memT, WwT, Mm);
  hipLaunchKernelGGL(k_pre2, dim3(64), dim3(256), 0, stream, Mm, W_w, W_b, Pb, pbias);
  hipLaunchKernelGGL(k_yw, dim3(4096), dim3(256), 0, stream, x, Pb, pbias, ywbf, Xs);
  hipLaunchKernelGGL(k_h, dim3(512), dim3(256), 0, stream,
                     Xs, WwT, W_b, a_vec, h, hT, Wh1, Wh2);
  hipLaunchKernelGGL(k_adj, dim3(1024), dim3(256), 0, stream,
                     h, hT, memT, Wh1, Wh2, cw, cwa, fc_w, fc_b, adjT);
  hipLaunchKernelGGL(k_out, dim3(1024), dim3(512), 0, stream,
                     ywbf, adjT, conv_b, emb, x, out);
}